// Round 8
// baseline (361.778 us; speedup 1.0000x reference)
//
#include <hip/hip_runtime.h>
#include <math.h>

#define B_ 8
#define S_ 1024
#define DM 512
#define H_ 8
#define DH 64

typedef _Float16 h4 __attribute__((ext_vector_type(4)));
typedef _Float16 h8 __attribute__((ext_vector_type(8)));
typedef float f4 __attribute__((ext_vector_type(4)));

#define MFMA16(a, b, c) __builtin_amdgcn_mfma_f32_16x16x32_f16(a, b, c, 0, 0, 0)

// ---------------------------------------------------------------------------
// Cast X (f32 row-major) -> f16 row-major. grid (4096, 3), 4 elems/thread.
// ---------------------------------------------------------------------------
__global__ __launch_bounds__(256) void cast_x(
    const float* __restrict__ x0, const float* __restrict__ x1,
    const float* __restrict__ x2, _Float16* __restrict__ y0,
    _Float16* __restrict__ y1, _Float16* __restrict__ y2) {
  const float* x = (blockIdx.y == 0) ? x0 : (blockIdx.y == 1) ? x1 : x2;
  _Float16* y = (blockIdx.y == 0) ? y0 : (blockIdx.y == 1) ? y1 : y2;
  size_t i = (size_t)blockIdx.x * 1024 + (size_t)threadIdx.x * 4;
  float4 v = *(const float4*)(x + i);
  h4 hv = {(_Float16)v.x, (_Float16)v.y, (_Float16)v.z, (_Float16)v.w};
  *(h4*)(y + i) = hv;
}

// ---------------------------------------------------------------------------
// Cast + transpose W [512][512] f32 -> Wt [n][k] f16. grid (8, 8, 4).
// ---------------------------------------------------------------------------
__global__ __launch_bounds__(256) void cast_w(
    const float* __restrict__ w0, const float* __restrict__ w1,
    const float* __restrict__ w2, const float* __restrict__ w3,
    _Float16* __restrict__ t0, _Float16* __restrict__ t1,
    _Float16* __restrict__ t2, _Float16* __restrict__ t3) {
  const float* W;
  _Float16* T;
  switch (blockIdx.z) {
    case 0: W = w0; T = t0; break;
    case 1: W = w1; T = t1; break;
    case 2: W = w2; T = t2; break;
    default: W = w3; T = t3; break;
  }
  __shared__ _Float16 ts[64][72];
  const int t = threadIdx.x;
  const int r = t >> 2, c0 = (t & 3) * 16;
  const int n0 = blockIdx.x * 64, k0 = blockIdx.y * 64;
#pragma unroll
  for (int i = 0; i < 4; i++) {
    float4 v = *(const float4*)&W[(size_t)(k0 + r) * 512 + n0 + c0 + i * 4];
    h4 hv = {(_Float16)v.x, (_Float16)v.y, (_Float16)v.z, (_Float16)v.w};
    *(h4*)&ts[r][c0 + i * 4] = hv;
  }
  __syncthreads();
  alignas(16) _Float16 outv[16];
#pragma unroll
  for (int i = 0; i < 16; i++) outv[i] = ts[c0 + i][r];
  *(uint4*)&T[(size_t)(n0 + r) * 512 + k0 + c0] = *(uint4*)&outv[0];
  *(uint4*)&T[(size_t)(n0 + r) * 512 + k0 + c0 + 8] = *(uint4*)&outv[8];
}

// ---------------------------------------------------------------------------
// Fused QKV projection GEMM, 128x128 tile. grid (4, 64, 3).
// DIRECT-FROM-L2 fragment loads, barrier-free K-loop, unroll 2.
// LDS used only for the coalesced-store epilogue (z==2 does V-transpose).
// ---------------------------------------------------------------------------
__global__ __launch_bounds__(256) void gemm_qkv(
    const _Float16* __restrict__ Xq, const _Float16* __restrict__ Xk,
    const _Float16* __restrict__ Xv, const _Float16* __restrict__ Wt,
    _Float16* __restrict__ Qh, _Float16* __restrict__ Kh,
    _Float16* __restrict__ Vth) {
  const int z = blockIdx.z;
  const int id = blockIdx.x + 4 * blockIdx.y;  // [0,256)
  const int c = id & 7, r = id >> 3;           // c = XCD slot
  const int by = c + 8 * (r & 7);              // [0,64)
  const int bx = r >> 3;                       // [0,4)
  const _Float16* A = (z == 0) ? Xq : (z == 1) ? Xk : Xv;
  const _Float16* Bt = Wt + (size_t)z * 512 * 512;
  __shared__ _Float16 Sh[128 * 144];  // epilogue staging only
  const int t = threadIdx.x, lane = t & 63, w = t >> 6;
  const int quad = lane >> 4, l16 = lane & 15;
  const int row0 = by * 128, col0 = bx * 128;
  const int wm = (w & 1) * 64, wn = (w >> 1) * 64;
  f4 acc[4][4] = {};
  const _Float16* Ab = A + (size_t)(row0 + wm + l16) * DM + quad * 8;
  const _Float16* Bb = Bt + (size_t)(col0 + wn + l16) * DM + quad * 8;
#pragma unroll 2
  for (int k0 = 0; k0 < DM; k0 += 64) {
    h8 af[4][2], bf[4][2];
#pragma unroll
    for (int m = 0; m < 4; m++) {
      const _Float16* ap = Ab + (size_t)m * 16 * DM + k0;
      const _Float16* bp = Bb + (size_t)m * 16 * DM + k0;
      af[m][0] = *(const h8*)ap;
      af[m][1] = *(const h8*)(ap + 32);
      bf[m][0] = *(const h8*)bp;
      bf[m][1] = *(const h8*)(bp + 32);
    }
#pragma unroll
    for (int m = 0; m < 4; m++)
#pragma unroll
      for (int n = 0; n < 4; n++) {
        acc[m][n] = MFMA16(af[m][0], bf[n][0], acc[m][n]);
        acc[m][n] = MFMA16(af[m][1], bf[n][1], acc[m][n]);
      }
  }
  if (z < 2) {
    _Float16* C = (z == 0) ? Qh : Kh;
#pragma unroll
    for (int m = 0; m < 4; m++)
#pragma unroll
      for (int n = 0; n < 4; n++)
#pragma unroll
        for (int reg = 0; reg < 4; reg++)
          Sh[(wm + m * 16 + quad * 4 + reg) * 144 + wn + n * 16 + l16] =
              (_Float16)acc[m][n][reg];
    __syncthreads();
    const int rr = t >> 4;        // 0..15
    const int cs = (t & 15) * 8;  // 0..120, 16B segments
#pragma unroll
    for (int i = 0; i < 8; i++) {
      int row = rr + 16 * i;
      *(uint4*)&C[(size_t)(row0 + row) * DM + col0 + cs] =
          *(uint4*)&Sh[row * 144 + cs];
    }
  } else {
    // V: stage TRANSPOSED [dm-col][s-row] so readback is contiguous in s.
#pragma unroll
    for (int m = 0; m < 4; m++)
#pragma unroll
      for (int n = 0; n < 4; n++) {
        h4 vv = {(_Float16)acc[m][n][0], (_Float16)acc[m][n][1],
                 (_Float16)acc[m][n][2], (_Float16)acc[m][n][3]};
        *(h4*)&Sh[(wn + n * 16 + l16) * 144 + wm + m * 16 + quad * 4] = vv;
      }
    __syncthreads();
    const int rr = t >> 4;        // 0..15 (dm-col within tile)
    const int cs = (t & 15) * 8;  // s-offset, 16B segments
    const int b = row0 >> 10, s0 = row0 & 1023;
#pragma unroll
    for (int i = 0; i < 8; i++) {
      int cg = col0 + rr + 16 * i;  // global dm column
      int h = cg >> 6, d = cg & 63;
      *(uint4*)&Vth[((size_t)(b * 8 + h) * 64 + d) * S_ + s0 + cs] =
          *(uint4*)&Sh[(rr + 16 * i) * 144 + cs];
    }
  }
}

// ---------------------------------------------------------------------------
// fc GEMM: out0 = ctx @ Wfc^T-layout, f32 out. 64x128 tile, grid (4, 128),
// XCD-swizzled. Direct-from-L2 fragment loads, barrier-free, unroll 2.
// ---------------------------------------------------------------------------
__global__ __launch_bounds__(256) void gemm_fc(
    const _Float16* __restrict__ A, const _Float16* __restrict__ Bt,
    float* __restrict__ C) {
  const int id = blockIdx.x + 4 * blockIdx.y;  // [0,512)
  const int c = id & 7, r = id >> 3;           // r in [0,64)
  const int by = c + 8 * (r & 15);             // [0,128)
  const int bx = r >> 4;                       // [0,4)
  const int t = threadIdx.x, lane = t & 63, w = t >> 6;
  const int quad = lane >> 4, l16 = lane & 15;
  const int row0 = by * 64, col0 = bx * 128;
  const int wm = (w & 1) * 32, wn = (w >> 1) * 64;
  f4 acc[2][4] = {};
  const _Float16* Ab = A + (size_t)(row0 + wm + l16) * DM + quad * 8;
  const _Float16* Bb = Bt + (size_t)(col0 + wn + l16) * DM + quad * 8;
#pragma unroll 2
  for (int k0 = 0; k0 < DM; k0 += 64) {
    h8 af[2][2], bf[4][2];
#pragma unroll
    for (int m = 0; m < 2; m++) {
      const _Float16* ap = Ab + (size_t)m * 16 * DM + k0;
      af[m][0] = *(const h8*)ap;
      af[m][1] = *(const h8*)(ap + 32);
    }
#pragma unroll
    for (int n = 0; n < 4; n++) {
      const _Float16* bp = Bb + (size_t)n * 16 * DM + k0;
      bf[n][0] = *(const h8*)bp;
      bf[n][1] = *(const h8*)(bp + 32);
    }
#pragma unroll
    for (int m = 0; m < 2; m++)
#pragma unroll
      for (int n = 0; n < 4; n++) {
        acc[m][n] = MFMA16(af[m][0], bf[n][0], acc[m][n]);
        acc[m][n] = MFMA16(af[m][1], bf[n][1], acc[m][n]);
      }
  }
#pragma unroll
  for (int m = 0; m < 2; m++)
#pragma unroll
    for (int n = 0; n < 4; n++)
#pragma unroll
      for (int reg = 0; reg < 4; reg++) {
        size_t row = row0 + wm + m * 16 + quad * 4 + reg;
        size_t col = col0 + wn + n * 16 + l16;
        C[row * DM + col] = acc[m][n][reg];
      }
}

// ---------------------------------------------------------------------------
// scores_avg + fused edge-mask precompute, TRANSPOSED fragments: QK^T is
// computed as mfma(K, Q) so each lane holds 4 CONSECUTIVE j-columns
// (j = wn+n*16+quad*4+reg, i = wm+m*16+l16). All global traffic vectorizes:
// mask int4, edge float4, out1 float4, Ehs h4. Ehs stores (edge-8) for
// flash's fixed-shift softmax (masked = -65504).
// Ehs layout: [((b*16 + j/64)*1024 + i)*64 + j%64], 8B-aligned groups.
// ---------------------------------------------------------------------------
__global__ __launch_bounds__(256) void scores_mfma(
    const _Float16* __restrict__ Qh, const _Float16* __restrict__ Kh,
    const int* __restrict__ mask, const float* __restrict__ edge,
    float* __restrict__ out1, _Float16* __restrict__ Ehs) {
  const int b = blockIdx.z;
  const int id = blockIdx.x + 8 * blockIdx.y;  // [0,64)
  const int iy = id & 7, jx = id >> 3;         // i-panel pinned per XCD
  const int i0 = iy * 128, j0 = jx * 128;
  const _Float16* A = Qh + (size_t)b * S_ * DM;
  const _Float16* Bt = Kh + (size_t)b * S_ * DM;
  const int t = threadIdx.x, lane = t & 63, w = t >> 6;
  const int quad = lane >> 4, l16 = lane & 15;
  const int wm = (w & 1) * 64, wn = (w >> 1) * 64;
  f4 acc[4][4] = {};
  const _Float16* Ab = A + (size_t)(i0 + wm + l16) * DM + quad * 8;
  const _Float16* Bb = Bt + (size_t)(j0 + wn + l16) * DM + quad * 8;
#pragma unroll 2
  for (int k0 = 0; k0 < DM; k0 += 64) {
    h8 af[4][2], bf[4][2];
#pragma unroll
    for (int m = 0; m < 4; m++) {
      const _Float16* ap = Ab + (size_t)m * 16 * DM + k0;
      const _Float16* bp = Bb + (size_t)m * 16 * DM + k0;
      af[m][0] = *(const h8*)ap;
      af[m][1] = *(const h8*)(ap + 32);
      bf[m][0] = *(const h8*)bp;
      bf[m][1] = *(const h8*)(bp + 32);
    }
    // swapped operands: acc[m][n] = K_n^T . Q_m -> rows j, cols i
#pragma unroll
    for (int m = 0; m < 4; m++)
#pragma unroll
      for (int n = 0; n < 4; n++) {
        acc[m][n] = MFMA16(bf[n][0], af[m][0], acc[m][n]);
        acc[m][n] = MFMA16(bf[n][1], af[m][1], acc[m][n]);
      }
  }
  const int jt = (j0 + wn) >> 6;  // constant per wave
#pragma unroll
  for (int m = 0; m < 4; m++) {
    size_t gi = i0 + wm + m * 16 + l16;
    size_t rowb = ((size_t)b * S_ + gi) * S_;
    size_t ehrow = (((size_t)b * 16 + jt) * 1024 + gi) * 64;
#pragma unroll
    for (int n = 0; n < 4; n++) {
      int jloc = n * 16 + quad * 4;  // j within the 64-wide jt tile
      size_t idx = rowb + j0 + wn + jloc;
      int4 mk4 = *(const int4*)&mask[idx];
      float4 e4 = *(const float4*)&edge[idx];
      float o[4];
      h4 ev;
      const int mk[4] = {mk4.x, mk4.y, mk4.z, mk4.w};
      const float ee[4] = {e4.x, e4.y, e4.z, e4.w};
#pragma unroll
      for (int reg = 0; reg < 4; reg++) {
        o[reg] = mk[reg] ? -1e9f : (acc[m][n][reg] * (1.0f / 64.0f) + ee[reg]);
        ev[reg] = mk[reg] ? (_Float16)(-65504.0f) : (_Float16)(ee[reg] - 8.0f);
      }
      *(float4*)&out1[idx] = make_float4(o[0], o[1], o[2], o[3]);
      *(h4*)&Ehs[ehrow + jloc] = ev;  // 8B store
    }
  }
}

// ---------------------------------------------------------------------------
// MFMA flash attention v9: fixed-shift softmax + TRANSPOSED QK^T fragments.
// QK^T computed as mfma(K, Q): fragment READS are identical (A/B frags have
// the same lane layout), but the output transposes so each lane holds 4
// consecutive k-values -> P-store to LDS is 8x h4 (8B) instead of 32x b16
// scalars (cuts the serial chain + bank conflicts). Ehs pre-shifted (-8) and
// pre-swizzled to 8B loads matching the transposed layout. l via P@ones MFMA.
// q-tile 128, 2 blocks/CU, LDS K/V staging + reg prefetch. grid (8, 64).
// ---------------------------------------------------------------------------
__global__ __launch_bounds__(256, 2) void flash_mfma(
    const _Float16* __restrict__ Qh, const _Float16* __restrict__ Kh,
    const _Float16* __restrict__ Vth, const _Float16* __restrict__ Ehs,
    _Float16* __restrict__ ctxh) {
  __shared__ _Float16 Ps[128][72], Ks[64][72], Vt[64][72];
  const int t = threadIdx.x, lane = t & 63, w = t >> 6;
  const int quad = lane >> 4, l16 = lane & 15;
  const int g = blockIdx.x + 8 * blockIdx.y;  // [0,512)
  const int c = g & 7, r = g >> 3;            // r in [0,64)
  const int bh = c + 8 * (r & 7);             // [0,64): (b,h) pinned per XCD
  const int qb = r >> 3;                      // [0,8)
  const int b = bh >> 3, h = bh & 7;
  const int q0 = qb * 128;
  const size_t bS = (size_t)b * S_;
  const int sr = t >> 3, sc = (t & 7) * 8;
  const int qw = w * 32;  // wave q-strip base within tile

  // stage Q (128x64) into Ps
#pragma unroll
  for (int i = 0; i < 4; i++)
    *(uint4*)&Ps[sr + 32 * i][sc] =
        *(const uint4*)&Qh[(bS + q0 + sr + 32 * i) * DM + h * DH + sc];
  __syncthreads();
  h8 aq[2][2];
#pragma unroll
  for (int m = 0; m < 2; m++)
#pragma unroll
    for (int k = 0; k < 2; k++)
      aq[m][k] = *(h8*)&Ps[qw + m * 16 + l16][k * 32 + quad * 8];
  // (no barrier needed: wave w only ever rewrites its own rows qw..qw+31)

  // prologue prefetch: K/V tile 0, Ehs tile 0 ([m][n] = 8B at col n*16+quad*4)
  uint4 kv[4];
  kv[0] = *(const uint4*)&Kh[(bS + sr) * DM + h * DH + sc];
  kv[1] = *(const uint4*)&Kh[(bS + sr + 32) * DM + h * DH + sc];
  kv[2] = *(const uint4*)&Vth[((size_t)bh * 64 + sr) * S_ + sc];
  kv[3] = *(const uint4*)&Vth[((size_t)bh * 64 + sr + 32) * S_ + sc];
  h4 evh[2][4];
#pragma unroll
  for (int m = 0; m < 2; m++)
#pragma unroll
    for (int n = 0; n < 4; n++)
      evh[m][n] = *(const h4*)&Ehs[(((size_t)b * 16 + 0) * 1024 + q0 + qw +
                                    m * 16 + l16) *
                                       64 +
                                   n * 16 + quad * 4];

  f4 acco[2][4] = {};
  f4 accl[2] = {};  // l accumulated as P @ ones via MFMA

  h8 vone;
#pragma unroll
  for (int i = 0; i < 8; i++) vone[i] = (_Float16)1.0f;

  for (int kb = 0; kb < S_; kb += 64) {
    __syncthreads();
    *(uint4*)&Ks[sr][sc] = kv[0];
    *(uint4*)&Ks[sr + 32][sc] = kv[1];
    *(uint4*)&Vt[sr][sc] = kv[2];
    *(uint4*)&Vt[sr + 32][sc] = kv[3];
    __syncthreads();
    const int kn = kb + 64;
    h4 evn[2][4];
    if (kn < S_) {
      kv[0] = *(const uint4*)&Kh[(bS + kn + sr) * DM + h * DH + sc];
      kv[1] = *(const uint4*)&Kh[(bS + kn + sr + 32) * DM + h * DH + sc];
      kv[2] = *(const uint4*)&Vth[((size_t)bh * 64 + sr) * S_ + kn + sc];
      kv[3] = *(const uint4*)&Vth[((size_t)bh * 64 + sr + 32) * S_ + kn + sc];
      const size_t ehb = ((size_t)b * 16 + (kn >> 6)) * 1024;
#pragma unroll
      for (int m = 0; m < 2; m++)
#pragma unroll
        for (int n = 0; n < 4; n++)
          evn[m][n] = *(const h4*)&Ehs[(ehb + q0 + qw + m * 16 + l16) * 64 +
                                       n * 16 + quad * 4];
    }
    // ---- QK^T (swapped): accs[m][n] = K_n^T . Q_m -> lane holds
    //      k = n*16+quad*4+reg (consecutive in reg), q = m*16+l16 ----
    f4 accs[2][4] = {};
#pragma unroll
    for (int n = 0; n < 4; n++) {
      h8 b0 = *(h8*)&Ks[n * 16 + l16][quad * 8];
      h8 b1 = *(h8*)&Ks[n * 16 + l16][32 + quad * 8];
#pragma unroll
      for (int m = 0; m < 2; m++) {
        accs[m][n] = MFMA16(b0, aq[m][0], accs[m][n]);
        accs[m][n] = MFMA16(b1, aq[m][1], accs[m][n]);
      }
    }
    // ---- P = exp(score + (e-8)) -> LDS as 8B h4 per (m,n) ----
#pragma unroll
    for (int m = 0; m < 2; m++)
#pragma unroll
      for (int n = 0; n < 4; n++) {
        h4 pv;
#pragma unroll
        for (int reg = 0; reg < 4; reg++)
          pv[reg] = (_Float16)__expf(accs[m][n][reg] * 0.125f +
                                     (float)evh[m][n][reg]);
        *(h4*)&Ps[qw + m * 16 + l16][n * 16 + quad * 4] = pv;
      }
    // ---- P @ V (+ l via P @ ones) ----
    h8 ap[2][2];
#pragma unroll
    for (int m = 0; m < 2; m++)
#pragma unroll
      for (int k = 0; k < 2; k++)
        ap[m][k] = *(h8*)&Ps[qw + m * 16 + l16][k * 32 + quad * 8];
#pragma unroll
    for (int d = 0; d < 4; d++) {
      h8 bv0 = *(h8*)&Vt[d * 16 + l16][quad * 8];
      h8 bv1 = *(h8*)&Vt[d * 16 + l16][32 + quad * 8];
#pragma unroll
      for (int m = 0; m < 2; m++) {
        acco[m][d] = MFMA16(ap[m][0], bv0, acco[m][d]);
        acco[m][d] = MFMA16(ap[m][1], bv1, acco[m][d]);
      }
    }
#pragma unroll
    for (int m = 0; m < 2; m++) {
      accl[m] = MFMA16(ap[m][0], vone, accl[m]);
      accl[m] = MFMA16(ap[m][1], vone, accl[m]);
    }
    if (kn < S_) {
#pragma unroll
      for (int m = 0; m < 2; m++)
#pragma unroll
        for (int n = 0; n < 4; n++) evh[m][n] = evn[m][n];
    }
  }
  // ---- epilogue: stage ctx tile (128x64) in Ps, coalesced stores ----
#pragma unroll
  for (int m = 0; m < 2; m++)
#pragma unroll
    for (int d = 0; d < 4; d++)
#pragma unroll
      for (int reg = 0; reg < 4; reg++)
        Ps[qw + m * 16 + quad * 4 + reg][d * 16 + l16] =
            (_Float16)(acco[m][d][reg] / accl[m][reg]);
  __syncthreads();
  const int orr = t >> 3, ocs = (t & 7) * 8;
#pragma unroll
  for (int i = 0; i < 4; i++) {
    int row = orr + 32 * i;
    *(uint4*)&ctxh[(bS + q0 + row) * DM + h * DH + ocs] =
        *(uint4*)&Ps[row][ocs];
  }
}

extern "C" void kernel_launch(void* const* d_in, const int* in_sizes, int n_in,
                              void* d_out, int out_size, void* d_ws,
                              size_t ws_size, hipStream_t stream) {
  const float* Xq = (const float*)d_in[0];
  const float* Xk = (const float*)d_in[1];
  const float* Xv = (const float*)d_in[2];
  const int* mask = (const int*)d_in[3];
  const float* edge = (const float*)d_in[4];
  const float* Wq = (const float*)d_in[5];
  const float* Wk = (const float*)d_in[6];
  const float* Wv = (const float*)d_in[7];
  const float* Wfc = (const float*)d_in[8];

  float* out0 = (float*)d_out;                // [B,S,DM] f32
  float* out1 = out0 + (size_t)B_ * S_ * DM;  // [B,S,S] f32

  const size_t NE = (size_t)B_ * S_ * DM;
  char* ws = (char*)d_ws;
  _Float16* Qh = (_Float16*)ws;
  _Float16* Kh = Qh + NE;
  _Float16* Vth = Kh + NE;   // per-head transposed V [bh*64+d][s]
  _Float16* Xhq = Vth + NE;  // later: ctxh
  _Float16* Xhk = Xhq + NE;
  _Float16* Xhv = Xhk + NE;
  _Float16* Wt = Xhv + NE;  // Wq,Wk,Wv,Wfc transposed f16 (contiguous)
  _Float16* Wtf = Wt + 3 * 512 * 512;
  _Float16* Ehs = Wt + 4 * 512 * 512;  // [B,S,S] f16, swizzled (e-8 / -65504)
  _Float16* ctxh = Xhq;

  dim3 blk(256);
  cast_x<<<dim3(4096, 3), blk, 0, stream>>>(Xq, Xk, Xv, Xhq, Xhk, Xhv);
  cast_w<<<dim3(8, 8, 4), blk, 0, stream>>>(Wq, Wk, Wv, Wfc, Wt,
                                            Wt + 512 * 512, Wt + 2 * 512 * 512,
                                            Wtf);
  gemm_qkv<<<dim3(4, 64, 3), blk, 0, stream>>>(Xhq, Xhk, Xhv, Wt, Qh, Kh, Vth);
  scores_mfma<<<dim3(8, 8, 8), blk, 0, stream>>>(Qh, Kh, mask, edge, out1,
                                                 Ehs);
  flash_mfma<<<dim3(8, 64), blk, 0, stream>>>(Qh, Kh, Vth, Ehs, ctxh);
  gemm_fc<<<dim3(4, 128), blk, 0, stream>>>(ctxh, Wtf, out0);
}

// Round 9
// 348.385 us; speedup vs baseline: 1.0384x; 1.0384x over previous
//
#include <hip/hip_runtime.h>
#include <math.h>

#define B_ 8
#define S_ 1024
#define DM 512
#define H_ 8
#define DH 64

typedef _Float16 h4 __attribute__((ext_vector_type(4)));
typedef _Float16 h8 __attribute__((ext_vector_type(8)));
typedef float f4 __attribute__((ext_vector_type(4)));

#define MFMA16(a, b, c) __builtin_amdgcn_mfma_f32_16x16x32_f16(a, b, c, 0, 0, 0)

// ---------------------------------------------------------------------------
// Cast X (f32 row-major) -> f16 row-major. grid (4096, 3), 4 elems/thread.
// ---------------------------------------------------------------------------
__global__ __launch_bounds__(256) void cast_x(
    const float* __restrict__ x0, const float* __restrict__ x1,
    const float* __restrict__ x2, _Float16* __restrict__ y0,
    _Float16* __restrict__ y1, _Float16* __restrict__ y2) {
  const float* x = (blockIdx.y == 0) ? x0 : (blockIdx.y == 1) ? x1 : x2;
  _Float16* y = (blockIdx.y == 0) ? y0 : (blockIdx.y == 1) ? y1 : y2;
  size_t i = (size_t)blockIdx.x * 1024 + (size_t)threadIdx.x * 4;
  float4 v = *(const float4*)(x + i);
  h4 hv = {(_Float16)v.x, (_Float16)v.y, (_Float16)v.z, (_Float16)v.w};
  *(h4*)(y + i) = hv;
}

// ---------------------------------------------------------------------------
// Cast + transpose W [512][512] f32 -> Wt [n][k] f16. grid (8, 8, 4).
// ---------------------------------------------------------------------------
__global__ __launch_bounds__(256) void cast_w(
    const float* __restrict__ w0, const float* __restrict__ w1,
    const float* __restrict__ w2, const float* __restrict__ w3,
    _Float16* __restrict__ t0, _Float16* __restrict__ t1,
    _Float16* __restrict__ t2, _Float16* __restrict__ t3) {
  const float* W;
  _Float16* T;
  switch (blockIdx.z) {
    case 0: W = w0; T = t0; break;
    case 1: W = w1; T = t1; break;
    case 2: W = w2; T = t2; break;
    default: W = w3; T = t3; break;
  }
  __shared__ _Float16 ts[64][72];
  const int t = threadIdx.x;
  const int r = t >> 2, c0 = (t & 3) * 16;
  const int n0 = blockIdx.x * 64, k0 = blockIdx.y * 64;
#pragma unroll
  for (int i = 0; i < 4; i++) {
    float4 v = *(const float4*)&W[(size_t)(k0 + r) * 512 + n0 + c0 + i * 4];
    h4 hv = {(_Float16)v.x, (_Float16)v.y, (_Float16)v.z, (_Float16)v.w};
    *(h4*)&ts[r][c0 + i * 4] = hv;
  }
  __syncthreads();
  alignas(16) _Float16 outv[16];
#pragma unroll
  for (int i = 0; i < 16; i++) outv[i] = ts[c0 + i][r];
  *(uint4*)&T[(size_t)(n0 + r) * 512 + k0 + c0] = *(uint4*)&outv[0];
  *(uint4*)&T[(size_t)(n0 + r) * 512 + k0 + c0 + 8] = *(uint4*)&outv[8];
}

// ---------------------------------------------------------------------------
// Fused QKV projection GEMM, 128x128 tile. grid (4, 64, 3).
// DIRECT-FROM-L2 fragment loads, barrier-free K-loop, unroll 2.
// LDS used only for the coalesced-store epilogue (z==2 does V-transpose).
// ---------------------------------------------------------------------------
__global__ __launch_bounds__(256) void gemm_qkv(
    const _Float16* __restrict__ Xq, const _Float16* __restrict__ Xk,
    const _Float16* __restrict__ Xv, const _Float16* __restrict__ Wt,
    _Float16* __restrict__ Qh, _Float16* __restrict__ Kh,
    _Float16* __restrict__ Vth) {
  const int z = blockIdx.z;
  const int id = blockIdx.x + 4 * blockIdx.y;  // [0,256)
  const int c = id & 7, r = id >> 3;           // c = XCD slot
  const int by = c + 8 * (r & 7);              // [0,64)
  const int bx = r >> 3;                       // [0,4)
  const _Float16* A = (z == 0) ? Xq : (z == 1) ? Xk : Xv;
  const _Float16* Bt = Wt + (size_t)z * 512 * 512;
  __shared__ _Float16 Sh[128 * 144];  // epilogue staging only
  const int t = threadIdx.x, lane = t & 63, w = t >> 6;
  const int quad = lane >> 4, l16 = lane & 15;
  const int row0 = by * 128, col0 = bx * 128;
  const int wm = (w & 1) * 64, wn = (w >> 1) * 64;
  f4 acc[4][4] = {};
  const _Float16* Ab = A + (size_t)(row0 + wm + l16) * DM + quad * 8;
  const _Float16* Bb = Bt + (size_t)(col0 + wn + l16) * DM + quad * 8;
#pragma unroll 2
  for (int k0 = 0; k0 < DM; k0 += 64) {
    h8 af[4][2], bf[4][2];
#pragma unroll
    for (int m = 0; m < 4; m++) {
      const _Float16* ap = Ab + (size_t)m * 16 * DM + k0;
      const _Float16* bp = Bb + (size_t)m * 16 * DM + k0;
      af[m][0] = *(const h8*)ap;
      af[m][1] = *(const h8*)(ap + 32);
      bf[m][0] = *(const h8*)bp;
      bf[m][1] = *(const h8*)(bp + 32);
    }
#pragma unroll
    for (int m = 0; m < 4; m++)
#pragma unroll
      for (int n = 0; n < 4; n++) {
        acc[m][n] = MFMA16(af[m][0], bf[n][0], acc[m][n]);
        acc[m][n] = MFMA16(af[m][1], bf[n][1], acc[m][n]);
      }
  }
  if (z < 2) {
    _Float16* C = (z == 0) ? Qh : Kh;
#pragma unroll
    for (int m = 0; m < 4; m++)
#pragma unroll
      for (int n = 0; n < 4; n++)
#pragma unroll
        for (int reg = 0; reg < 4; reg++)
          Sh[(wm + m * 16 + quad * 4 + reg) * 144 + wn + n * 16 + l16] =
              (_Float16)acc[m][n][reg];
    __syncthreads();
    const int rr = t >> 4;        // 0..15
    const int cs = (t & 15) * 8;  // 0..120, 16B segments
#pragma unroll
    for (int i = 0; i < 8; i++) {
      int row = rr + 16 * i;
      *(uint4*)&C[(size_t)(row0 + row) * DM + col0 + cs] =
          *(uint4*)&Sh[row * 144 + cs];
    }
  } else {
    // V: stage TRANSPOSED [dm-col][s-row] so readback is contiguous in s.
#pragma unroll
    for (int m = 0; m < 4; m++)
#pragma unroll
      for (int n = 0; n < 4; n++) {
        h4 vv = {(_Float16)acc[m][n][0], (_Float16)acc[m][n][1],
                 (_Float16)acc[m][n][2], (_Float16)acc[m][n][3]};
        *(h4*)&Sh[(wn + n * 16 + l16) * 144 + wm + m * 16 + quad * 4] = vv;
      }
    __syncthreads();
    const int rr = t >> 4;        // 0..15 (dm-col within tile)
    const int cs = (t & 15) * 8;  // s-offset, 16B segments
    const int b = row0 >> 10, s0 = row0 & 1023;
#pragma unroll
    for (int i = 0; i < 8; i++) {
      int cg = col0 + rr + 16 * i;  // global dm column
      int h = cg >> 6, d = cg & 63;
      *(uint4*)&Vth[((size_t)(b * 8 + h) * 64 + d) * S_ + s0 + cs] =
          *(uint4*)&Sh[(rr + 16 * i) * 144 + cs];
    }
  }
}

// ---------------------------------------------------------------------------
// fc GEMM: out0 = ctx @ Wfc^T-layout, f32 out. 64x128 tile, grid (4, 128),
// XCD-swizzled. Direct-from-L2 fragment loads, barrier-free, unroll 2.
// ---------------------------------------------------------------------------
__global__ __launch_bounds__(256) void gemm_fc(
    const _Float16* __restrict__ A, const _Float16* __restrict__ Bt,
    float* __restrict__ C) {
  const int id = blockIdx.x + 4 * blockIdx.y;  // [0,512)
  const int c = id & 7, r = id >> 3;           // r in [0,64)
  const int by = c + 8 * (r & 15);             // [0,128)
  const int bx = r >> 4;                       // [0,4)
  const int t = threadIdx.x, lane = t & 63, w = t >> 6;
  const int quad = lane >> 4, l16 = lane & 15;
  const int row0 = by * 64, col0 = bx * 128;
  const int wm = (w & 1) * 32, wn = (w >> 1) * 64;
  f4 acc[2][4] = {};
  const _Float16* Ab = A + (size_t)(row0 + wm + l16) * DM + quad * 8;
  const _Float16* Bb = Bt + (size_t)(col0 + wn + l16) * DM + quad * 8;
#pragma unroll 2
  for (int k0 = 0; k0 < DM; k0 += 64) {
    h8 af[2][2], bf[4][2];
#pragma unroll
    for (int m = 0; m < 2; m++) {
      const _Float16* ap = Ab + (size_t)m * 16 * DM + k0;
      af[m][0] = *(const h8*)ap;
      af[m][1] = *(const h8*)(ap + 32);
    }
#pragma unroll
    for (int n = 0; n < 4; n++) {
      const _Float16* bp = Bb + (size_t)n * 16 * DM + k0;
      bf[n][0] = *(const h8*)bp;
      bf[n][1] = *(const h8*)(bp + 32);
    }
#pragma unroll
    for (int m = 0; m < 2; m++)
#pragma unroll
      for (int n = 0; n < 4; n++) {
        acc[m][n] = MFMA16(af[m][0], bf[n][0], acc[m][n]);
        acc[m][n] = MFMA16(af[m][1], bf[n][1], acc[m][n]);
      }
  }
#pragma unroll
  for (int m = 0; m < 2; m++)
#pragma unroll
    for (int n = 0; n < 4; n++)
#pragma unroll
      for (int reg = 0; reg < 4; reg++) {
        size_t row = row0 + wm + m * 16 + quad * 4 + reg;
        size_t col = col0 + wn + n * 16 + l16;
        C[row * DM + col] = acc[m][n][reg];
      }
}

// ---------------------------------------------------------------------------
// scores_avg + fused edge-mask precompute, TRANSPOSED fragments (mfma(K,Q)):
// lane holds 4 consecutive j (j = j0+wn+n*16+quad*4+reg) at i = wm+m*16+l16.
// Global traffic: mask int4, edge float4, out1 float4, Ehs h4.
// Ehs layout (fixed-shift e-8, masked = -65504), flat f16 index:
//   E(b,jt,q,k) = (((b*16+jt)*64 + q/16)*16 + (k/16)*4 + (k%16)/4)*64
//                 + (q%16)*4 + (k%4)
// Per-(m,n) wave store/load = 512B contiguous (round-8 lesson: the round-7
// Ehs swizzle left 128B-strided 8B accesses in flash -> 10us regression).
// ---------------------------------------------------------------------------
__global__ __launch_bounds__(256) void scores_mfma(
    const _Float16* __restrict__ Qh, const _Float16* __restrict__ Kh,
    const int* __restrict__ mask, const float* __restrict__ edge,
    float* __restrict__ out1, _Float16* __restrict__ Ehs) {
  const int b = blockIdx.z;
  const int id = blockIdx.x + 8 * blockIdx.y;  // [0,64)
  const int iy = id & 7, jx = id >> 3;         // i-panel pinned per XCD
  const int i0 = iy * 128, j0 = jx * 128;
  const _Float16* A = Qh + (size_t)b * S_ * DM;
  const _Float16* Bt = Kh + (size_t)b * S_ * DM;
  const int t = threadIdx.x, lane = t & 63, w = t >> 6;
  const int quad = lane >> 4, l16 = lane & 15;
  const int wm = (w & 1) * 64, wn = (w >> 1) * 64;
  f4 acc[4][4] = {};
  const _Float16* Ab = A + (size_t)(i0 + wm + l16) * DM + quad * 8;
  const _Float16* Bb = Bt + (size_t)(j0 + wn + l16) * DM + quad * 8;
#pragma unroll 2
  for (int k0 = 0; k0 < DM; k0 += 64) {
    h8 af[4][2], bf[4][2];
#pragma unroll
    for (int m = 0; m < 4; m++) {
      const _Float16* ap = Ab + (size_t)m * 16 * DM + k0;
      const _Float16* bp = Bb + (size_t)m * 16 * DM + k0;
      af[m][0] = *(const h8*)ap;
      af[m][1] = *(const h8*)(ap + 32);
      bf[m][0] = *(const h8*)bp;
      bf[m][1] = *(const h8*)(bp + 32);
    }
    // swapped operands: acc[m][n] = K_n^T . Q_m -> rows j, cols i
#pragma unroll
    for (int m = 0; m < 4; m++)
#pragma unroll
      for (int n = 0; n < 4; n++) {
        acc[m][n] = MFMA16(bf[n][0], af[m][0], acc[m][n]);
        acc[m][n] = MFMA16(bf[n][1], af[m][1], acc[m][n]);
      }
  }
  const int jt = (j0 + wn) >> 6;  // constant per wave
#pragma unroll
  for (int m = 0; m < 4; m++) {
    size_t gi = i0 + wm + m * 16 + l16;  // q row
    size_t rowb = ((size_t)b * S_ + gi) * S_;
    const size_t qg = (size_t)(i0 + wm + m * 16) >> 4;  // q/16 (l16 < 16)
    const size_t ehb = (((size_t)b * 16 + jt) * 64 + qg) * 16;
#pragma unroll
    for (int n = 0; n < 4; n++) {
      int jloc = n * 16 + quad * 4;  // j within the 64-wide jt tile
      size_t idx = rowb + j0 + wn + jloc;
      int4 mk4 = *(const int4*)&mask[idx];
      float4 e4 = *(const float4*)&edge[idx];
      float o[4];
      h4 ev;
      const int mk[4] = {mk4.x, mk4.y, mk4.z, mk4.w};
      const float ee[4] = {e4.x, e4.y, e4.z, e4.w};
#pragma unroll
      for (int reg = 0; reg < 4; reg++) {
        o[reg] = mk[reg] ? -1e9f : (acc[m][n][reg] * (1.0f / 64.0f) + ee[reg]);
        ev[reg] = mk[reg] ? (_Float16)(-65504.0f) : (_Float16)(ee[reg] - 8.0f);
      }
      *(float4*)&out1[idx] = make_float4(o[0], o[1], o[2], o[3]);
      // 8B store; per (m,n) wave-store = quad*128B + l16*8B = 512B contiguous
      *(h4*)&Ehs[(ehb + n * 4 + quad) * 64 + l16 * 4] = ev;
    }
  }
}

// ---------------------------------------------------------------------------
// MFMA flash attention v10: fixed-shift softmax + transposed QK^T fragments
// (round 8) + COALESCED Ehs layout matching the transposed orientation:
// every Ehs wave-load is 512B contiguous (fixes round-8's 128B-strided 8B
// loads). P-store 8x h4, l via P@ones MFMA. q-tile 128, 2 blocks/CU, LDS
// K/V staging + reg prefetch. grid (8, 64).
// ---------------------------------------------------------------------------
__global__ __launch_bounds__(256, 2) void flash_mfma(
    const _Float16* __restrict__ Qh, const _Float16* __restrict__ Kh,
    const _Float16* __restrict__ Vth, const _Float16* __restrict__ Ehs,
    _Float16* __restrict__ ctxh) {
  __shared__ _Float16 Ps[128][72], Ks[64][72], Vt[64][72];
  const int t = threadIdx.x, lane = t & 63, w = t >> 6;
  const int quad = lane >> 4, l16 = lane & 15;
  const int g = blockIdx.x + 8 * blockIdx.y;  // [0,512)
  const int c = g & 7, r = g >> 3;            // r in [0,64)
  const int bh = c + 8 * (r & 7);             // [0,64): (b,h) pinned per XCD
  const int qb = r >> 3;                      // [0,8)
  const int b = bh >> 3, h = bh & 7;
  const int q0 = qb * 128;
  const size_t bS = (size_t)b * S_;
  const int sr = t >> 3, sc = (t & 7) * 8;
  const int qw = w * 32;  // wave q-strip base within tile
  const size_t qg0 = (size_t)(q0 + qw) >> 4;  // q/16 base for this wave

  // stage Q (128x64) into Ps
#pragma unroll
  for (int i = 0; i < 4; i++)
    *(uint4*)&Ps[sr + 32 * i][sc] =
        *(const uint4*)&Qh[(bS + q0 + sr + 32 * i) * DM + h * DH + sc];
  __syncthreads();
  h8 aq[2][2];
#pragma unroll
  for (int m = 0; m < 2; m++)
#pragma unroll
    for (int k = 0; k < 2; k++)
      aq[m][k] = *(h8*)&Ps[qw + m * 16 + l16][k * 32 + quad * 8];
  // (no barrier needed: wave w only ever rewrites its own rows qw..qw+31)

  // prologue prefetch: K/V tile 0, Ehs tile 0
  uint4 kv[4];
  kv[0] = *(const uint4*)&Kh[(bS + sr) * DM + h * DH + sc];
  kv[1] = *(const uint4*)&Kh[(bS + sr + 32) * DM + h * DH + sc];
  kv[2] = *(const uint4*)&Vth[((size_t)bh * 64 + sr) * S_ + sc];
  kv[3] = *(const uint4*)&Vth[((size_t)bh * 64 + sr + 32) * S_ + sc];
  h4 evh[2][4];
#pragma unroll
  for (int m = 0; m < 2; m++) {
    const size_t ehb = (((size_t)b * 16 + 0) * 64 + qg0 + m) * 16;
#pragma unroll
    for (int n = 0; n < 4; n++)
      evh[m][n] = *(const h4*)&Ehs[(ehb + n * 4 + quad) * 64 + l16 * 4];
  }

  f4 acco[2][4] = {};
  f4 accl[2] = {};  // l accumulated as P @ ones via MFMA

  h8 vone;
#pragma unroll
  for (int i = 0; i < 8; i++) vone[i] = (_Float16)1.0f;

  for (int kb = 0; kb < S_; kb += 64) {
    __syncthreads();
    *(uint4*)&Ks[sr][sc] = kv[0];
    *(uint4*)&Ks[sr + 32][sc] = kv[1];
    *(uint4*)&Vt[sr][sc] = kv[2];
    *(uint4*)&Vt[sr + 32][sc] = kv[3];
    __syncthreads();
    const int kn = kb + 64;
    h4 evn[2][4];
    if (kn < S_) {
      kv[0] = *(const uint4*)&Kh[(bS + kn + sr) * DM + h * DH + sc];
      kv[1] = *(const uint4*)&Kh[(bS + kn + sr + 32) * DM + h * DH + sc];
      kv[2] = *(const uint4*)&Vth[((size_t)bh * 64 + sr) * S_ + kn + sc];
      kv[3] = *(const uint4*)&Vth[((size_t)bh * 64 + sr + 32) * S_ + kn + sc];
#pragma unroll
      for (int m = 0; m < 2; m++) {
        const size_t ehb = (((size_t)b * 16 + (kn >> 6)) * 64 + qg0 + m) * 16;
#pragma unroll
        for (int n = 0; n < 4; n++)
          evn[m][n] = *(const h4*)&Ehs[(ehb + n * 4 + quad) * 64 + l16 * 4];
      }
    }
    // ---- QK^T (swapped): accs[m][n] = K_n^T . Q_m -> lane holds
    //      k = n*16+quad*4+reg (consecutive in reg), q = m*16+l16 ----
    f4 accs[2][4] = {};
#pragma unroll
    for (int n = 0; n < 4; n++) {
      h8 b0 = *(h8*)&Ks[n * 16 + l16][quad * 8];
      h8 b1 = *(h8*)&Ks[n * 16 + l16][32 + quad * 8];
#pragma unroll
      for (int m = 0; m < 2; m++) {
        accs[m][n] = MFMA16(b0, aq[m][0], accs[m][n]);
        accs[m][n] = MFMA16(b1, aq[m][1], accs[m][n]);
      }
    }
    // ---- P = exp(score + (e-8)) -> LDS as 8B h4 per (m,n) ----
#pragma unroll
    for (int m = 0; m < 2; m++)
#pragma unroll
      for (int n = 0; n < 4; n++) {
        h4 pv;
#pragma unroll
        for (int reg = 0; reg < 4; reg++)
          pv[reg] = (_Float16)__expf(accs[m][n][reg] * 0.125f +
                                     (float)evh[m][n][reg]);
        *(h4*)&Ps[qw + m * 16 + l16][n * 16 + quad * 4] = pv;
      }
    // ---- P @ V (+ l via P @ ones) ----
    h8 ap[2][2];
#pragma unroll
    for (int m = 0; m < 2; m++)
#pragma unroll
      for (int k = 0; k < 2; k++)
        ap[m][k] = *(h8*)&Ps[qw + m * 16 + l16][k * 32 + quad * 8];
#pragma unroll
    for (int d = 0; d < 4; d++) {
      h8 bv0 = *(h8*)&Vt[d * 16 + l16][quad * 8];
      h8 bv1 = *(h8*)&Vt[d * 16 + l16][32 + quad * 8];
#pragma unroll
      for (int m = 0; m < 2; m++) {
        acco[m][d] = MFMA16(ap[m][0], bv0, acco[m][d]);
        acco[m][d] = MFMA16(ap[m][1], bv1, acco[m][d]);
      }
    }
#pragma unroll
    for (int m = 0; m < 2; m++) {
      accl[m] = MFMA16(ap[m][0], vone, accl[m]);
      accl[m] = MFMA16(ap[m][1], vone, accl[m]);
    }
    if (kn < S_) {
#pragma unroll
      for (int m = 0; m < 2; m++)
#pragma unroll
        for (int n = 0; n < 4; n++) evh[m][n] = evn[m][n];
    }
  }
  // ---- epilogue: stage ctx tile (128x64) in Ps, coalesced stores ----
#pragma unroll
  for (int m = 0; m < 2; m++)
#pragma unroll
    for (int d = 0; d < 4; d++)
#pragma unroll
      for (int reg = 0; reg < 4; reg++)
        Ps[qw + m * 16 + quad * 4 + reg][d * 16 + l16] =
            (_Float16)(acco[m][d][reg] / accl[m][reg]);
  __syncthreads();
  const int orr = t >> 3, ocs = (t & 7) * 8;
#pragma unroll
  for (int i = 0; i < 4; i++) {
    int row = orr + 32 * i;
    *(uint4*)&ctxh[(bS + q0 + row) * DM + h * DH + ocs] =
        *(uint4*)&Ps[row][ocs];
  }
}

extern "C" void kernel_launch(void* const* d_in, const int* in_sizes, int n_in,
                              void* d_out, int out_size, void* d_ws,
                              size_t ws_size, hipStream_t stream) {
  const float* Xq = (const float*)d_in[0];
  const float* Xk = (const float*)d_in[1];
  const float* Xv = (const float*)d_in[2];
  const int* mask = (const int*)d_in[3];
  const float* edge = (const float*)d_in[4];
  const float* Wq = (const float*)d_in[5];
  const float* Wk = (const float*)d_in[6];
  const float* Wv = (const float*)d_in[7];
  const float* Wfc = (const float*)d_in[8];

  float* out0 = (float*)d_out;                // [B,S,DM] f32
  float* out1 = out0 + (size_t)B_ * S_ * DM;  // [B,S,S] f32

  const size_t NE = (size_t)B_ * S_ * DM;
  char* ws = (char*)d_ws;
  _Float16* Qh = (_Float16*)ws;
  _Float16* Kh = Qh + NE;
  _Float16* Vth = Kh + NE;   // per-head transposed V [bh*64+d][s]
  _Float16* Xhq = Vth + NE;  // later: ctxh
  _Float16* Xhk = Xhq + NE;
  _Float16* Xhv = Xhk + NE;
  _Float16* Wt = Xhv + NE;  // Wq,Wk,Wv,Wfc transposed f16 (contiguous)
  _Float16* Wtf = Wt + 3 * 512 * 512;
  _Float16* Ehs = Wt + 4 * 512 * 512;  // [B,S,S] f16, swizzled (e-8 / -65504)
  _Float16* ctxh = Xhq;

  dim3 blk(256);
  cast_x<<<dim3(4096, 3), blk, 0, stream>>>(Xq, Xk, Xv, Xhq, Xhk, Xhv);
  cast_w<<<dim3(8, 8, 4), blk, 0, stream>>>(Wq, Wk, Wv, Wfc, Wt,
                                            Wt + 512 * 512, Wt + 2 * 512 * 512,
                                            Wtf);
  gemm_qkv<<<dim3(4, 64, 3), blk, 0, stream>>>(Xhq, Xhk, Xhv, Wt, Qh, Kh, Vth);
  scores_mfma<<<dim3(8, 8, 8), blk, 0, stream>>>(Qh, Kh, mask, edge, out1,
                                                 Ehs);
  flash_mfma<<<dim3(8, 64), blk, 0, stream>>>(Qh, Kh, Vth, Ehs, ctxh);
  gemm_fc<<<dim3(4, 128), blk, 0, stream>>>(ctxh, Wtf, out0);
}

// Round 10
// 347.716 us; speedup vs baseline: 1.0404x; 1.0019x over previous
//
#include <hip/hip_runtime.h>
#include <math.h>

#define B_ 8
#define S_ 1024
#define DM 512
#define H_ 8
#define DH 64

typedef _Float16 h4 __attribute__((ext_vector_type(4)));
typedef _Float16 h8 __attribute__((ext_vector_type(8)));
typedef float f4 __attribute__((ext_vector_type(4)));

#define MFMA16(a, b, c) __builtin_amdgcn_mfma_f32_16x16x32_f16(a, b, c, 0, 0, 0)

// ---------------------------------------------------------------------------
// Cast X (f32 row-major) -> f16 row-major. grid (4096, 3), 4 elems/thread.
// ---------------------------------------------------------------------------
__global__ __launch_bounds__(256) void cast_x(
    const float* __restrict__ x0, const float* __restrict__ x1,
    const float* __restrict__ x2, _Float16* __restrict__ y0,
    _Float16* __restrict__ y1, _Float16* __restrict__ y2) {
  const float* x = (blockIdx.y == 0) ? x0 : (blockIdx.y == 1) ? x1 : x2;
  _Float16* y = (blockIdx.y == 0) ? y0 : (blockIdx.y == 1) ? y1 : y2;
  size_t i = (size_t)blockIdx.x * 1024 + (size_t)threadIdx.x * 4;
  float4 v = *(const float4*)(x + i);
  h4 hv = {(_Float16)v.x, (_Float16)v.y, (_Float16)v.z, (_Float16)v.w};
  *(h4*)(y + i) = hv;
}

// ---------------------------------------------------------------------------
// Cast + transpose W [512][512] f32 -> Wt [n][k] f16. grid (8, 8, 4).
// ---------------------------------------------------------------------------
__global__ __launch_bounds__(256) void cast_w(
    const float* __restrict__ w0, const float* __restrict__ w1,
    const float* __restrict__ w2, const float* __restrict__ w3,
    _Float16* __restrict__ t0, _Float16* __restrict__ t1,
    _Float16* __restrict__ t2, _Float16* __restrict__ t3) {
  const float* W;
  _Float16* T;
  switch (blockIdx.z) {
    case 0: W = w0; T = t0; break;
    case 1: W = w1; T = t1; break;
    case 2: W = w2; T = t2; break;
    default: W = w3; T = t3; break;
  }
  __shared__ _Float16 ts[64][72];
  const int t = threadIdx.x;
  const int r = t >> 2, c0 = (t & 3) * 16;
  const int n0 = blockIdx.x * 64, k0 = blockIdx.y * 64;
#pragma unroll
  for (int i = 0; i < 4; i++) {
    float4 v = *(const float4*)&W[(size_t)(k0 + r) * 512 + n0 + c0 + i * 4];
    h4 hv = {(_Float16)v.x, (_Float16)v.y, (_Float16)v.z, (_Float16)v.w};
    *(h4*)&ts[r][c0 + i * 4] = hv;
  }
  __syncthreads();
  alignas(16) _Float16 outv[16];
#pragma unroll
  for (int i = 0; i < 16; i++) outv[i] = ts[c0 + i][r];
  *(uint4*)&T[(size_t)(n0 + r) * 512 + k0 + c0] = *(uint4*)&outv[0];
  *(uint4*)&T[(size_t)(n0 + r) * 512 + k0 + c0 + 8] = *(uint4*)&outv[8];
}

// ---------------------------------------------------------------------------
// Fused QKV projection GEMM, 128x128 tile. grid (4, 64, 3).
// DIRECT-FROM-L2 fragment loads, barrier-free K-loop, unroll 2.
// LDS used only for the coalesced-store epilogue (z==2 does V-transpose).
// ---------------------------------------------------------------------------
__global__ __launch_bounds__(256) void gemm_qkv(
    const _Float16* __restrict__ Xq, const _Float16* __restrict__ Xk,
    const _Float16* __restrict__ Xv, const _Float16* __restrict__ Wt,
    _Float16* __restrict__ Qh, _Float16* __restrict__ Kh,
    _Float16* __restrict__ Vth) {
  const int z = blockIdx.z;
  const int id = blockIdx.x + 4 * blockIdx.y;  // [0,256)
  const int c = id & 7, r = id >> 3;           // c = XCD slot
  const int by = c + 8 * (r & 7);              // [0,64)
  const int bx = r >> 3;                       // [0,4)
  const _Float16* A = (z == 0) ? Xq : (z == 1) ? Xk : Xv;
  const _Float16* Bt = Wt + (size_t)z * 512 * 512;
  __shared__ _Float16 Sh[128 * 144];  // epilogue staging only
  const int t = threadIdx.x, lane = t & 63, w = t >> 6;
  const int quad = lane >> 4, l16 = lane & 15;
  const int row0 = by * 128, col0 = bx * 128;
  const int wm = (w & 1) * 64, wn = (w >> 1) * 64;
  f4 acc[4][4] = {};
  const _Float16* Ab = A + (size_t)(row0 + wm + l16) * DM + quad * 8;
  const _Float16* Bb = Bt + (size_t)(col0 + wn + l16) * DM + quad * 8;
#pragma unroll 2
  for (int k0 = 0; k0 < DM; k0 += 64) {
    h8 af[4][2], bf[4][2];
#pragma unroll
    for (int m = 0; m < 4; m++) {
      const _Float16* ap = Ab + (size_t)m * 16 * DM + k0;
      const _Float16* bp = Bb + (size_t)m * 16 * DM + k0;
      af[m][0] = *(const h8*)ap;
      af[m][1] = *(const h8*)(ap + 32);
      bf[m][0] = *(const h8*)bp;
      bf[m][1] = *(const h8*)(bp + 32);
    }
#pragma unroll
    for (int m = 0; m < 4; m++)
#pragma unroll
      for (int n = 0; n < 4; n++) {
        acc[m][n] = MFMA16(af[m][0], bf[n][0], acc[m][n]);
        acc[m][n] = MFMA16(af[m][1], bf[n][1], acc[m][n]);
      }
  }
  if (z < 2) {
    _Float16* C = (z == 0) ? Qh : Kh;
#pragma unroll
    for (int m = 0; m < 4; m++)
#pragma unroll
      for (int n = 0; n < 4; n++)
#pragma unroll
        for (int reg = 0; reg < 4; reg++)
          Sh[(wm + m * 16 + quad * 4 + reg) * 144 + wn + n * 16 + l16] =
              (_Float16)acc[m][n][reg];
    __syncthreads();
    const int rr = t >> 4;        // 0..15
    const int cs = (t & 15) * 8;  // 0..120, 16B segments
#pragma unroll
    for (int i = 0; i < 8; i++) {
      int row = rr + 16 * i;
      *(uint4*)&C[(size_t)(row0 + row) * DM + col0 + cs] =
          *(uint4*)&Sh[row * 144 + cs];
    }
  } else {
    // V: stage TRANSPOSED [dm-col][s-row] so readback is contiguous in s.
#pragma unroll
    for (int m = 0; m < 4; m++)
#pragma unroll
      for (int n = 0; n < 4; n++) {
        h4 vv = {(_Float16)acc[m][n][0], (_Float16)acc[m][n][1],
                 (_Float16)acc[m][n][2], (_Float16)acc[m][n][3]};
        *(h4*)&Sh[(wn + n * 16 + l16) * 144 + wm + m * 16 + quad * 4] = vv;
      }
    __syncthreads();
    const int rr = t >> 4;        // 0..15 (dm-col within tile)
    const int cs = (t & 15) * 8;  // s-offset, 16B segments
    const int b = row0 >> 10, s0 = row0 & 1023;
#pragma unroll
    for (int i = 0; i < 8; i++) {
      int cg = col0 + rr + 16 * i;  // global dm column
      int h = cg >> 6, d = cg & 63;
      *(uint4*)&Vth[((size_t)(b * 8 + h) * 64 + d) * S_ + s0 + cs] =
          *(uint4*)&Sh[(rr + 16 * i) * 144 + cs];
    }
  }
}

// ---------------------------------------------------------------------------
// fc GEMM: out0 = ctx @ Wfc^T-layout, f32 out. 64x128 tile, grid (4, 128),
// XCD-swizzled. Direct-from-L2 fragment loads, barrier-free, unroll 2.
// ---------------------------------------------------------------------------
__global__ __launch_bounds__(256) void gemm_fc(
    const _Float16* __restrict__ A, const _Float16* __restrict__ Bt,
    float* __restrict__ C) {
  const int id = blockIdx.x + 4 * blockIdx.y;  // [0,512)
  const int c = id & 7, r = id >> 3;           // r in [0,64)
  const int by = c + 8 * (r & 15);             // [0,128)
  const int bx = r >> 4;                       // [0,4)
  const int t = threadIdx.x, lane = t & 63, w = t >> 6;
  const int quad = lane >> 4, l16 = lane & 15;
  const int row0 = by * 64, col0 = bx * 128;
  const int wm = (w & 1) * 32, wn = (w >> 1) * 64;
  f4 acc[2][4] = {};
  const _Float16* Ab = A + (size_t)(row0 + wm + l16) * DM + quad * 8;
  const _Float16* Bb = Bt + (size_t)(col0 + wn + l16) * DM + quad * 8;
#pragma unroll 2
  for (int k0 = 0; k0 < DM; k0 += 64) {
    h8 af[2][2], bf[4][2];
#pragma unroll
    for (int m = 0; m < 2; m++) {
      const _Float16* ap = Ab + (size_t)m * 16 * DM + k0;
      af[m][0] = *(const h8*)ap;
      af[m][1] = *(const h8*)(ap + 32);
    }
#pragma unroll
    for (int n = 0; n < 4; n++) {
      const _Float16* bp = Bb + (size_t)n * 16 * DM + k0;
      bf[n][0] = *(const h8*)bp;
      bf[n][1] = *(const h8*)(bp + 32);
    }
#pragma unroll
    for (int m = 0; m < 2; m++)
#pragma unroll
      for (int n = 0; n < 4; n++) {
        acc[m][n] = MFMA16(af[m][0], bf[n][0], acc[m][n]);
        acc[m][n] = MFMA16(af[m][1], bf[n][1], acc[m][n]);
      }
  }
#pragma unroll
  for (int m = 0; m < 2; m++)
#pragma unroll
    for (int n = 0; n < 4; n++)
#pragma unroll
      for (int reg = 0; reg < 4; reg++) {
        size_t row = row0 + wm + m * 16 + quad * 4 + reg;
        size_t col = col0 + wn + n * 16 + l16;
        C[row * DM + col] = acc[m][n][reg];
      }
}

// ---------------------------------------------------------------------------
// scores_avg + fused edge-mask precompute, TRANSPOSED fragments (mfma(K,Q)):
// lane holds 4 consecutive j (j = j0+wn+n*16+quad*4+reg) at i = wm+m*16+l16.
// Global traffic: mask int4, edge float4, out1 float4, Ehs h4.
// Ehs layout (fixed-shift e-8, masked = -65504), flat f16 index:
//   E(b,jt,q,k) = (((b*16+jt)*64 + q/16)*16 + (k/16)*4 + (k%16)/4)*64
//                 + (q%16)*4 + (k%4)
// Per-(m,n) wave store/load = 512B contiguous.
// ---------------------------------------------------------------------------
__global__ __launch_bounds__(256) void scores_mfma(
    const _Float16* __restrict__ Qh, const _Float16* __restrict__ Kh,
    const int* __restrict__ mask, const float* __restrict__ edge,
    float* __restrict__ out1, _Float16* __restrict__ Ehs) {
  const int b = blockIdx.z;
  const int id = blockIdx.x + 8 * blockIdx.y;  // [0,64)
  const int iy = id & 7, jx = id >> 3;         // i-panel pinned per XCD
  const int i0 = iy * 128, j0 = jx * 128;
  const _Float16* A = Qh + (size_t)b * S_ * DM;
  const _Float16* Bt = Kh + (size_t)b * S_ * DM;
  const int t = threadIdx.x, lane = t & 63, w = t >> 6;
  const int quad = lane >> 4, l16 = lane & 15;
  const int wm = (w & 1) * 64, wn = (w >> 1) * 64;
  f4 acc[4][4] = {};
  const _Float16* Ab = A + (size_t)(i0 + wm + l16) * DM + quad * 8;
  const _Float16* Bb = Bt + (size_t)(j0 + wn + l16) * DM + quad * 8;
#pragma unroll 2
  for (int k0 = 0; k0 < DM; k0 += 64) {
    h8 af[4][2], bf[4][2];
#pragma unroll
    for (int m = 0; m < 4; m++) {
      const _Float16* ap = Ab + (size_t)m * 16 * DM + k0;
      const _Float16* bp = Bb + (size_t)m * 16 * DM + k0;
      af[m][0] = *(const h8*)ap;
      af[m][1] = *(const h8*)(ap + 32);
      bf[m][0] = *(const h8*)bp;
      bf[m][1] = *(const h8*)(bp + 32);
    }
    // swapped operands: acc[m][n] = K_n^T . Q_m -> rows j, cols i
#pragma unroll
    for (int m = 0; m < 4; m++)
#pragma unroll
      for (int n = 0; n < 4; n++) {
        acc[m][n] = MFMA16(bf[n][0], af[m][0], acc[m][n]);
        acc[m][n] = MFMA16(bf[n][1], af[m][1], acc[m][n]);
      }
  }
  const int jt = (j0 + wn) >> 6;  // constant per wave
#pragma unroll
  for (int m = 0; m < 4; m++) {
    size_t gi = i0 + wm + m * 16 + l16;  // q row
    size_t rowb = ((size_t)b * S_ + gi) * S_;
    const size_t qg = (size_t)(i0 + wm + m * 16) >> 4;  // q/16 (l16 < 16)
    const size_t ehb = (((size_t)b * 16 + jt) * 64 + qg) * 16;
#pragma unroll
    for (int n = 0; n < 4; n++) {
      int jloc = n * 16 + quad * 4;  // j within the 64-wide jt tile
      size_t idx = rowb + j0 + wn + jloc;
      int4 mk4 = *(const int4*)&mask[idx];
      float4 e4 = *(const float4*)&edge[idx];
      float o[4];
      h4 ev;
      const int mk[4] = {mk4.x, mk4.y, mk4.z, mk4.w};
      const float ee[4] = {e4.x, e4.y, e4.z, e4.w};
#pragma unroll
      for (int reg = 0; reg < 4; reg++) {
        o[reg] = mk[reg] ? -1e9f : (acc[m][n][reg] * (1.0f / 64.0f) + ee[reg]);
        ev[reg] = mk[reg] ? (_Float16)(-65504.0f) : (_Float16)(ee[reg] - 8.0f);
      }
      *(float4*)&out1[idx] = make_float4(o[0], o[1], o[2], o[3]);
      // 8B store; per (m,n) wave-store = quad*128B + l16*8B = 512B contiguous
      *(h4*)&Ehs[(ehb + n * 4 + quad) * 64 + l16 * 4] = ev;
    }
  }
}

// ---------------------------------------------------------------------------
// MFMA flash attention v11: double-buffered K/V LDS -> ONE barrier per
// iteration (was 2). With fixed-shift softmax + accl-via-MFMA there is no
// cross-iteration state beyond the linear acco/accl sums, so iter kb can
// ds_write tile kb+1 into buf[cur^1] (regs loaded an iteration ago) WHILE
// computing on buf[cur]; the end-of-iteration barrier provides both
// guarantees (writes visible; reads of buf[cur^1] drained 2 iters back).
// Barrier count 32 -> 17; ds_writes overlap MFMA/exp across waves.
// Transposed QK^T (mfma(K,Q)) + coalesced Ehs + P-store 8x h4 as round 9.
// LDS 55.3KB, 2 blocks/CU. grid (8, 64).
// ---------------------------------------------------------------------------
__global__ __launch_bounds__(256, 2) void flash_mfma(
    const _Float16* __restrict__ Qh, const _Float16* __restrict__ Kh,
    const _Float16* __restrict__ Vth, const _Float16* __restrict__ Ehs,
    _Float16* __restrict__ ctxh) {
  __shared__ _Float16 Ps[128][72];
  __shared__ _Float16 Ks[2][64][72], Vt[2][64][72];
  const int t = threadIdx.x, lane = t & 63, w = t >> 6;
  const int quad = lane >> 4, l16 = lane & 15;
  const int g = blockIdx.x + 8 * blockIdx.y;  // [0,512)
  const int c = g & 7, r = g >> 3;            // r in [0,64)
  const int bh = c + 8 * (r & 7);             // [0,64): (b,h) pinned per XCD
  const int qb = r >> 3;                      // [0,8)
  const int b = bh >> 3, h = bh & 7;
  const int q0 = qb * 128;
  const size_t bS = (size_t)b * S_;
  const int sr = t >> 3, sc = (t & 7) * 8;
  const int qw = w * 32;  // wave q-strip base within tile
  const size_t qg0 = (size_t)(q0 + qw) >> 4;  // q/16 base for this wave

  // stage Q (128x64) into Ps
#pragma unroll
  for (int i = 0; i < 4; i++)
    *(uint4*)&Ps[sr + 32 * i][sc] =
        *(const uint4*)&Qh[(bS + q0 + sr + 32 * i) * DM + h * DH + sc];

  // prologue: load K/V tile 0, stage into buf 0
  uint4 kv[4];
  kv[0] = *(const uint4*)&Kh[(bS + sr) * DM + h * DH + sc];
  kv[1] = *(const uint4*)&Kh[(bS + sr + 32) * DM + h * DH + sc];
  kv[2] = *(const uint4*)&Vth[((size_t)bh * 64 + sr) * S_ + sc];
  kv[3] = *(const uint4*)&Vth[((size_t)bh * 64 + sr + 32) * S_ + sc];
  *(uint4*)&Ks[0][sr][sc] = kv[0];
  *(uint4*)&Ks[0][sr + 32][sc] = kv[1];
  *(uint4*)&Vt[0][sr][sc] = kv[2];
  *(uint4*)&Vt[0][sr + 32][sc] = kv[3];
  __syncthreads();  // Ps (Q) ready + buf0 ready

  h8 aq[2][2];
#pragma unroll
  for (int m = 0; m < 2; m++)
#pragma unroll
    for (int k = 0; k < 2; k++)
      aq[m][k] = *(h8*)&Ps[qw + m * 16 + l16][k * 32 + quad * 8];

  // prefetch K/V tile 1 into regs, Ehs tile 0 into regs
  kv[0] = *(const uint4*)&Kh[(bS + 64 + sr) * DM + h * DH + sc];
  kv[1] = *(const uint4*)&Kh[(bS + 64 + sr + 32) * DM + h * DH + sc];
  kv[2] = *(const uint4*)&Vth[((size_t)bh * 64 + sr) * S_ + 64 + sc];
  kv[3] = *(const uint4*)&Vth[((size_t)bh * 64 + sr + 32) * S_ + 64 + sc];
  h4 evh[2][4];
#pragma unroll
  for (int m = 0; m < 2; m++) {
    const size_t ehb = (((size_t)b * 16 + 0) * 64 + qg0 + m) * 16;
#pragma unroll
    for (int n = 0; n < 4; n++)
      evh[m][n] = *(const h4*)&Ehs[(ehb + n * 4 + quad) * 64 + l16 * 4];
  }

  f4 acco[2][4] = {};
  f4 accl[2] = {};  // l accumulated as P @ ones via MFMA

  h8 vone;
#pragma unroll
  for (int i = 0; i < 8; i++) vone[i] = (_Float16)1.0f;

  for (int kb = 0; kb < S_; kb += 64) {
    const int cur = (kb >> 6) & 1;
    const int nxt = cur ^ 1;
    const int kn = kb + 64;
    // ---- stage tile kb+1 into buf[nxt] (regs loaded last iter) ----
    if (kn < S_) {
      *(uint4*)&Ks[nxt][sr][sc] = kv[0];
      *(uint4*)&Ks[nxt][sr + 32][sc] = kv[1];
      *(uint4*)&Vt[nxt][sr][sc] = kv[2];
      *(uint4*)&Vt[nxt][sr + 32][sc] = kv[3];
    }
    // ---- issue loads for tile kb+2 (overlap compute) ----
    if (kn + 64 < S_) {
      kv[0] = *(const uint4*)&Kh[(bS + kn + 64 + sr) * DM + h * DH + sc];
      kv[1] = *(const uint4*)&Kh[(bS + kn + 64 + sr + 32) * DM + h * DH + sc];
      kv[2] = *(const uint4*)&Vth[((size_t)bh * 64 + sr) * S_ + kn + 64 + sc];
      kv[3] =
          *(const uint4*)&Vth[((size_t)bh * 64 + sr + 32) * S_ + kn + 64 + sc];
    }
    h4 evn[2][4];
    if (kn < S_) {
#pragma unroll
      for (int m = 0; m < 2; m++) {
        const size_t ehb = (((size_t)b * 16 + (kn >> 6)) * 64 + qg0 + m) * 16;
#pragma unroll
        for (int n = 0; n < 4; n++)
          evn[m][n] = *(const h4*)&Ehs[(ehb + n * 4 + quad) * 64 + l16 * 4];
      }
    }
    // ---- QK^T (swapped) on buf[cur]: lane holds k = n*16+quad*4+reg ----
    f4 accs[2][4] = {};
#pragma unroll
    for (int n = 0; n < 4; n++) {
      h8 b0 = *(h8*)&Ks[cur][n * 16 + l16][quad * 8];
      h8 b1 = *(h8*)&Ks[cur][n * 16 + l16][32 + quad * 8];
#pragma unroll
      for (int m = 0; m < 2; m++) {
        accs[m][n] = MFMA16(b0, aq[m][0], accs[m][n]);
        accs[m][n] = MFMA16(b1, aq[m][1], accs[m][n]);
      }
    }
    // ---- P = exp(score + (e-8)) -> LDS as 8B h4 per (m,n) ----
#pragma unroll
    for (int m = 0; m < 2; m++)
#pragma unroll
      for (int n = 0; n < 4; n++) {
        h4 pv;
#pragma unroll
        for (int reg = 0; reg < 4; reg++)
          pv[reg] = (_Float16)__expf(accs[m][n][reg] * 0.125f +
                                     (float)evh[m][n][reg]);
        *(h4*)&Ps[qw + m * 16 + l16][n * 16 + quad * 4] = pv;
      }
    // ---- P @ V on buf[cur] (+ l via P @ ones) ----
    h8 ap[2][2];
#pragma unroll
    for (int m = 0; m < 2; m++)
#pragma unroll
      for (int k = 0; k < 2; k++)
        ap[m][k] = *(h8*)&Ps[qw + m * 16 + l16][k * 32 + quad * 8];
#pragma unroll
    for (int d = 0; d < 4; d++) {
      h8 bv0 = *(h8*)&Vt[cur][d * 16 + l16][quad * 8];
      h8 bv1 = *(h8*)&Vt[cur][d * 16 + l16][32 + quad * 8];
#pragma unroll
      for (int m = 0; m < 2; m++) {
        acco[m][d] = MFMA16(ap[m][0], bv0, acco[m][d]);
        acco[m][d] = MFMA16(ap[m][1], bv1, acco[m][d]);
      }
    }
#pragma unroll
    for (int m = 0; m < 2; m++) {
      accl[m] = MFMA16(ap[m][0], vone, accl[m]);
      accl[m] = MFMA16(ap[m][1], vone, accl[m]);
    }
    if (kn < S_) {
#pragma unroll
      for (int m = 0; m < 2; m++)
#pragma unroll
        for (int n = 0; n < 4; n++) evh[m][n] = evn[m][n];
    }
    __syncthreads();  // single per-iter barrier: buf[nxt] ready, buf[cur] free
  }
  // ---- epilogue: stage ctx tile (128x64) in Ps, coalesced stores ----
#pragma unroll
  for (int m = 0; m < 2; m++)
#pragma unroll
    for (int d = 0; d < 4; d++)
#pragma unroll
      for (int reg = 0; reg < 4; reg++)
        Ps[qw + m * 16 + quad * 4 + reg][d * 16 + l16] =
            (_Float16)(acco[m][d][reg] / accl[m][reg]);
  __syncthreads();
  const int orr = t >> 3, ocs = (t & 7) * 8;
#pragma unroll
  for (int i = 0; i < 4; i++) {
    int row = orr + 32 * i;
    *(uint4*)&ctxh[(bS + q0 + row) * DM + h * DH + ocs] =
        *(uint4*)&Ps[row][ocs];
  }
}

extern "C" void kernel_launch(void* const* d_in, const int* in_sizes, int n_in,
                              void* d_out, int out_size, void* d_ws,
                              size_t ws_size, hipStream_t stream) {
  const float* Xq = (const float*)d_in[0];
  const float* Xk = (const float*)d_in[1];
  const float* Xv = (const float*)d_in[2];
  const int* mask = (const int*)d_in[3];
  const float* edge = (const float*)d_in[4];
  const float* Wq = (const float*)d_in[5];
  const float* Wk = (const float*)d_in[6];
  const float* Wv = (const float*)d_in[7];
  const float* Wfc = (const float*)d_in[8];

  float* out0 = (float*)d_out;                // [B,S,DM] f32
  float* out1 = out0 + (size_t)B_ * S_ * DM;  // [B,S,S] f32

  const size_t NE = (size_t)B_ * S_ * DM;
  char* ws = (char*)d_ws;
  _Float16* Qh = (_Float16*)ws;
  _Float16* Kh = Qh + NE;
  _Float16* Vth = Kh + NE;   // per-head transposed V [bh*64+d][s]
  _Float16* Xhq = Vth + NE;  // later: ctxh
  _Float16* Xhk = Xhq + NE;
  _Float16* Xhv = Xhk + NE;
  _Float16* Wt = Xhv + NE;  // Wq,Wk,Wv,Wfc transposed f16 (contiguous)
  _Float16* Wtf = Wt + 3 * 512 * 512;
  _Float16* Ehs = Wt + 4 * 512 * 512;  // [B,S,S] f16, swizzled (e-8 / -65504)
  _Float16* ctxh = Xhq;

  dim3 blk(256);
  cast_x<<<dim3(4096, 3), blk, 0, stream>>>(Xq, Xk, Xv, Xhq, Xhk, Xhv);
  cast_w<<<dim3(8, 8, 4), blk, 0, stream>>>(Wq, Wk, Wv, Wfc, Wt,
                                            Wt + 512 * 512, Wt + 2 * 512 * 512,
                                            Wtf);
  gemm_qkv<<<dim3(4, 64, 3), blk, 0, stream>>>(Xhq, Xhk, Xhv, Wt, Qh, Kh, Vth);
  scores_mfma<<<dim3(8, 8, 8), blk, 0, stream>>>(Qh, Kh, mask, edge, out1,
                                                 Ehs);
  flash_mfma<<<dim3(8, 64), blk, 0, stream>>>(Qh, Kh, Vth, Ehs, ctxh);
  gemm_fc<<<dim3(4, 128), blk, 0, stream>>>(ctxh, Wtf, out0);
}